// Round 1
// baseline (9801.318 us; speedup 1.0000x reference)
//
#include <hip/hip_runtime.h>
#include <math.h>

#define BB 64
#define TT 512
#define EE 128
#define HH 256
#define NK 9

// ws byte offsets
#define OFF_TICK  524288ULL
#define OFF_HS    528384ULL
#define OFF_FEATS (528384ULL + 134217728ULL)   // hs = 2*512*256*64*8 bytes

// ---------------- init: h_buf parity0 from h0, zero tickets ----------------
__global__ void init_kernel(double* __restrict__ hbuf, int* __restrict__ tick,
                            const float* __restrict__ h0) {
  int gid = blockIdx.x * 256 + threadIdx.x;
  if (gid < 2 * HH * BB) {                 // 32768
    int d = gid >> 14;
    int r = gid & 16383;
    int k = r >> 6, bb = r & 63;
    // hbuf layout: [(parity*2 + dir)][k][b], parity0
    hbuf[(size_t)d * 16384 + k * 64 + bb] = (double)h0[d * 16384 + bb * HH + k];
  }
  if (gid < 256) tick[gid] = 0;
}

// ---------------- persistent recurrent kernel ----------------
// grid = 256 blocks (dir = bid>>7, slice s = bid&127 owns hidden units 2s,2s+1)
// 256 threads: b = tid&63, rp = tid>>6; thread computes local gate rows rp, rp+4
// local row r -> gate g=r>>1, unit offset uo=r&1, global row = g*256 + u0 + uo
__launch_bounds__(256, 1)
__global__ void recur_kernel(const int* __restrict__ sent, const float* __restrict__ emb,
                             const float* __restrict__ WihF, const float* __restrict__ WhhF,
                             const float* __restrict__ bihF, const float* __restrict__ bhhF,
                             const float* __restrict__ WihB, const float* __restrict__ WhhB,
                             const float* __restrict__ bihB, const float* __restrict__ bhhB,
                             const float* __restrict__ c0,
                             double* __restrict__ hbuf, int* __restrict__ tick,
                             double* __restrict__ hsout) {
  extern __shared__ double sm[];
  double* dWhh  = sm;            // 8*256 = 2048
  double* dWih  = sm + 2048;     // 8*128 = 1024
  double* dbias = sm + 3072;     // 8
  double* g_l   = sm + 3080;     // 8*64 = 512
  double* hch   = sm + 4096;     // 2 chunks x 4096 (64k x 64b)
  double* x_l   = sm + 12288;    // 128*64 = 8192   -> total 20480 doubles = 163840 B

  const int tid = threadIdx.x;
  const int dir = blockIdx.x >> 7;
  const int s   = blockIdx.x & 127;
  const int u0  = s * 2;
  const int b   = tid & 63;
  const int rp  = tid >> 6;
  const int r0 = rp, r1 = rp + 4;

  const float* Wih = dir ? WihB : WihF;
  const float* Whh = dir ? WhhB : WhhF;
  const float* bih = dir ? bihB : bihF;
  const float* bhh = dir ? bhhB : bhhF;

  // preload weight slices as f64
  for (int j = 0; j < 8; ++j) {
    int idx = tid * 8 + j;                  // 0..2047
    int r = idx >> 8, k = idx & 255;
    int grow = (r >> 1) * HH + u0 + (r & 1);
    dWhh[idx] = (double)Whh[grow * HH + k];
  }
  for (int j = 0; j < 4; ++j) {
    int idx = tid * 4 + j;                  // 0..1023
    int r = idx >> 7, e = idx & 127;
    int grow = (r >> 1) * HH + u0 + (r & 1);
    dWih[idx] = (double)Wih[grow * EE + e];
  }
  if (tid < 8) {
    int grow = (tid >> 1) * HH + u0 + (tid & 1);
    dbias[tid] = (double)bih[grow] + (double)bhh[grow];
  }
  double creg = 0.0;
  if (tid < 128) creg = (double)c0[dir * (BB * HH) + (tid & 63) * HH + u0 + (tid >> 6)];
  __syncthreads();

  for (int i = 0; i < TT; ++i) {
    const int tq = dir ? (TT - 1 - i) : i;

    // ---- stage x_t (emb gather) into LDS as f64 ----
    {
      int rowb = tid >> 2, part = tid & 3;
      int tok = sent[rowb * TT + tq];
      const float4* er = (const float4*)(emb + (size_t)tok * EE + part * 32);
      #pragma unroll
      for (int m = 0; m < 8; ++m) {
        float4 v = er[m];
        int e = part * 32 + m * 4;
        x_l[(e + 0) * 64 + rowb] = (double)v.x;
        x_l[(e + 1) * 64 + rowb] = (double)v.y;
        x_l[(e + 2) * 64 + rowb] = (double)v.z;
        x_l[(e + 3) * 64 + rowb] = (double)v.w;
      }
    }
    __syncthreads();

    // ---- x-part of gates ----
    double xa0 = dbias[r0], xa1 = dbias[r1];
    #pragma unroll 4
    for (int e = 0; e < EE; ++e) {
      double xe = x_l[e * 64 + b];
      xa0 += xe * dWih[r0 * EE + e];
      xa1 += xe * dWih[r1 * EE + e];
    }

    // ---- wait for all h slices of this direction (step i) ----
    if (tid < 128) {
      const int* tp = tick + dir * 128 + tid;
      while (__hip_atomic_load(tp, __ATOMIC_RELAXED, __HIP_MEMORY_SCOPE_AGENT) < i)
        __builtin_amdgcn_s_sleep(1);
    }
    __syncthreads();
    __builtin_amdgcn_fence(__ATOMIC_ACQUIRE, "agent");  // invalidate stale L2 lines

    // ---- h-part: chunked global->LDS double-buffer overlapped with FMA ----
    const double* hsrc = hbuf + (size_t)((i & 1) * 2 + dir) * 16384;
    double rr[16];
    #pragma unroll
    for (int j = 0; j < 16; ++j) rr[j] = hsrc[j * 256 + tid];
    #pragma unroll
    for (int j = 0; j < 16; ++j) hch[j * 256 + tid] = rr[j];
    double a0 = xa0, a1 = xa1;
    for (int c = 0; c < 4; ++c) {
      if (c < 3) {
        #pragma unroll
        for (int j = 0; j < 16; ++j) rr[j] = hsrc[(c + 1) * 4096 + j * 256 + tid];
      }
      __syncthreads();
      const double* hc  = hch + (c & 1) * 4096;
      const double* wr0 = dWhh + r0 * HH + c * 64;
      const double* wr1 = dWhh + r1 * HH + c * 64;
      #pragma unroll 8
      for (int k2 = 0; k2 < 64; ++k2) {
        double hv = hc[k2 * 64 + b];
        a0 += hv * wr0[k2];
        a1 += hv * wr1[k2];
      }
      if (c < 3) {
        double* hw = hch + ((c + 1) & 1) * 4096;
        #pragma unroll
        for (int j = 0; j < 16; ++j) hw[j * 256 + tid] = rr[j];
      }
    }
    __syncthreads();
    g_l[r0 * 64 + b] = a0;
    g_l[r1 * 64 + b] = a1;
    __syncthreads();

    // ---- pointwise LSTM cell update (threads 0..127 own (b, unit)) ----
    if (tid < 128) {
      int uo = tid >> 6, bb2 = tid & 63;
      double iv = g_l[(0 + uo) * 64 + bb2];   // r = 0*2+uo
      double fv = g_l[(2 + uo) * 64 + bb2];   // r = 1*2+uo
      double gv = g_l[(4 + uo) * 64 + bb2];   // r = 2*2+uo
      double ov = g_l[(6 + uo) * 64 + bb2];   // r = 3*2+uo
      double is = 1.0 / (1.0 + exp(-iv));
      double fs = 1.0 / (1.0 + exp(-fv));
      double gs = tanh(gv);
      double os = 1.0 / (1.0 + exp(-ov));
      creg = fs * creg + is * gs;
      double hval = os * tanh(creg);
      int u = u0 + uo;
      __hip_atomic_store(&hbuf[(size_t)(((i + 1) & 1) * 2 + dir) * 16384 + u * 64 + bb2],
                         hval, __ATOMIC_RELAXED, __HIP_MEMORY_SCOPE_AGENT);
      hsout[((size_t)(dir * TT + tq) * HH + u) * 64 + bb2] = hval;
    }
    __syncthreads();   // drains vmcnt for all waves before ticket
    if (tid == 0)
      __hip_atomic_store(&tick[dir * 128 + s], i + 1, __ATOMIC_RELAXED, __HIP_MEMORY_SCOPE_AGENT);
  }
}

// ---------------- feats = [hf|hb] @ Wout^T + bout ----------------
__global__ void feats_kernel(const double* __restrict__ hs, const float* __restrict__ Wout,
                             const float* __restrict__ bout, double* __restrict__ feats) {
  __shared__ double wl[NK * 2 * HH];   // 4608 doubles
  __shared__ double bl[NK];
  int tid = threadIdx.x, t = blockIdx.x;
  for (int idx = tid; idx < NK * 2 * HH; idx += 256) wl[idx] = (double)Wout[idx];
  if (tid < NK) bl[tid] = (double)bout[tid];
  __syncthreads();
  if (tid < 192) {
    int bb = tid & 63, kg = tid >> 6;   // kg 0..2 -> k = kg*3 + j
    double acc0 = bl[kg * 3 + 0], acc1 = bl[kg * 3 + 1], acc2 = bl[kg * 3 + 2];
    for (int d = 0; d < 2; ++d) {
      const double* hp = hs + ((size_t)(d * TT + t) * HH) * 64 + bb;
      const double* w0 = wl + (kg * 3 + 0) * 2 * HH + d * HH;
      const double* w1 = wl + (kg * 3 + 1) * 2 * HH + d * HH;
      const double* w2 = wl + (kg * 3 + 2) * 2 * HH + d * HH;
      for (int u = 0; u < HH; ++u) {
        double hv = hp[(size_t)u * 64];
        acc0 += hv * w0[u];
        acc1 += hv * w1[u];
        acc2 += hv * w2[u];
      }
    }
    double* fp = feats + ((size_t)bb * TT + t) * NK + kg * 3;
    fp[0] = acc0; fp[1] = acc1; fp[2] = acc2;
  }
}

// ---------------- viterbi decode (one block per batch row) ----------------
__global__ void viterbi_kernel(const double* __restrict__ feats, const float* __restrict__ start,
                               const float* __restrict__ endv, const float* __restrict__ trans,
                               int* __restrict__ out) {
  __shared__ double sc[NK];
  __shared__ double tr[NK * NK];
  __shared__ unsigned char hist[TT - 1][16];
  __shared__ unsigned char tags[TT];
  int lane = threadIdx.x, b = blockIdx.x;
  for (int idx = lane; idx < NK * NK; idx += 64) tr[idx] = (double)trans[idx];
  const double* fb = feats + (size_t)b * TT * NK;
  if (lane < NK) sc[lane] = (double)start[lane] + fb[lane];
  __syncthreads();
  double ftn = (lane < NK) ? fb[NK + lane] : 0.0;
  for (int t = 1; t < TT; ++t) {
    double ft = ftn;
    if (t + 1 < TT && lane < NK) ftn = fb[(size_t)(t + 1) * NK + lane];
    double best = -1e300; int arg = 0;
    if (lane < NK) {
      #pragma unroll
      for (int p = 0; p < NK; ++p) {
        double v = sc[p] + tr[p * NK + lane];
        if (v > best) { best = v; arg = p; }   // strict > keeps first index (jnp.argmax)
      }
      hist[t - 1][lane] = (unsigned char)arg;
    }
    __syncthreads();
    if (lane < NK) sc[lane] = best + ft;   // mask is all-true
    __syncthreads();
  }
  if (lane < NK) sc[lane] += (double)endv[lane];
  __syncthreads();
  if (lane == 0) {
    double best = -1e300; int tag = 0;
    for (int n = 0; n < NK; ++n) if (sc[n] > best) { best = sc[n]; tag = n; }
    tags[TT - 1] = (unsigned char)tag;
    for (int t = TT - 2; t >= 0; --t) { tag = hist[t][tag]; tags[t] = (unsigned char)tag; }
  }
  __syncthreads();
  for (int j = lane; j < TT; j += 64) out[b * TT + j] = (int)tags[j];
}

// ---------------- launcher ----------------
extern "C" void kernel_launch(void* const* d_in, const int* in_sizes, int n_in,
                              void* d_out, int out_size, void* d_ws, size_t ws_size,
                              hipStream_t stream) {
  const int*   sent = (const int*)  d_in[0];
  // d_in[1] = mask (all true) -- unused
  const float* emb  = (const float*)d_in[2];
  const float* WihF = (const float*)d_in[3];
  const float* WhhF = (const float*)d_in[4];
  const float* bihF = (const float*)d_in[5];
  const float* bhhF = (const float*)d_in[6];
  const float* WihB = (const float*)d_in[7];
  const float* WhhB = (const float*)d_in[8];
  const float* bihB = (const float*)d_in[9];
  const float* bhhB = (const float*)d_in[10];
  const float* Wout = (const float*)d_in[11];
  const float* bout = (const float*)d_in[12];
  const float* stv  = (const float*)d_in[13];
  const float* env  = (const float*)d_in[14];
  const float* trv  = (const float*)d_in[15];
  const float* h0   = (const float*)d_in[16];
  const float* c0   = (const float*)d_in[17];

  char* ws = (char*)d_ws;
  double* hbuf  = (double*)ws;                 // 2 parity x 2 dir x 256 x 64 f64
  int*    tick  = (int*)(ws + OFF_TICK);       // 256 tickets
  double* hs    = (double*)(ws + OFF_HS);      // [dir][t][u][b] f64
  double* feats = (double*)(ws + OFF_FEATS);   // [b][t][9] f64
  int* out = (int*)d_out;

  hipFuncSetAttribute((const void*)recur_kernel,
                      hipFuncAttributeMaxDynamicSharedMemorySize, 163840);

  init_kernel<<<128, 256, 0, stream>>>(hbuf, tick, h0);
  recur_kernel<<<256, 256, 163840, stream>>>(sent, emb, WihF, WhhF, bihF, bhhF,
                                             WihB, WhhB, bihB, bhhB, c0, hbuf, tick, hs);
  feats_kernel<<<TT, 256, 0, stream>>>(hs, Wout, bout, feats);
  viterbi_kernel<<<BB, 64, 0, stream>>>(feats, stv, env, trv, out);
}